// Round 4
// baseline (738.300 us; speedup 1.0000x reference)
//
#include <hip/hip_runtime.h>
#include <stdint.h>

// HashGrid forward, R6.
// R5 post-mortem: forced MLP batching HURT hash8 (312->343 us, Occ 81->48%)
// -> gather phase is REQUEST-THROUGHPUT-bound (per-XCD L2 request rate, ~10
// req/cy measured vs ~16 ceiling), not latency-bound. Both merge rewrites
// (R4b, R5) regressed 201 -> ~380 us; R3's merge is restored VERBATIM here
// (it measured 201 us) and left alone.
// R6 change (hash8 only): cut L2 request count 25% via aligned float4 pair
// loads. Hash structure: for even cx, idx(cx+1) = idx(cx)^1 (adjacent
// entries) -> loading 16B at tab4[idx>>1] and selecting the half with idx&1
// makes the two x-corner loads hit the SAME address for even cx (MSHR/L1
// merge -> 1 L2 request instead of 2). Dense levels 8/9: same float4-select
// trick pairs truly adjacent corners. Keep R4b's serial per-point schedule
// (measured 312; R5's batching hurt).
//
// Correctness-critical (unchanged, passed at 4.8e-7): pos = x*scale + 0.5 as
// separate __fmul_rn/__fadd_rn (no FMA -> floor() cell matches numpy);
// per-corner weights w = wx*wy; fmaf accumulation order
// (0,0),(0,1),(1,0),(1,1) from 0.0f (acc_quad passed bit-identical in R5);
// ws round-trips bits via u64 NT store / plain read.

constexpr int      kNPoints = 2097152;
constexpr uint32_t kT       = 524288u;      // 2^19
constexpr uint32_t kTMask   = kT - 1u;
constexpr uint32_t kPrimeY  = 2654435761u;  // tcnn 2D spatial-hash prime

__device__ __forceinline__ float2 nt_load_f2(const float2* p) {
    union { unsigned long long u; float2 f2; } u;
    u.u = __builtin_nontemporal_load(reinterpret_cast<const unsigned long long*>(p));
    return u.f2;
}

__device__ __forceinline__ void nt_store_f2(float2* p, float2 v) {
    union { unsigned long long u; float2 f2; } u; u.f2 = v;
    __builtin_nontemporal_store(u.u, reinterpret_cast<unsigned long long*>(p));
}

// scale = 16*1.5^l - 1, exactly fp32-representable for all 16 levels.
__device__ __host__ inline void level_consts(int l, float& sc, uint32_t& re, int& dense) {
    const float ksc[16] = {
        15.0f, 23.0f, 35.0f, 53.0f, 80.0f, 120.5f, 181.25f, 272.375f,
        409.0625f, 614.09375f, 921.640625f, 1382.9609375f,
        2074.94140625f, 3112.912109375f, 4669.8681640625f, 7005.30224609375f};
    const uint32_t kre[16] = {16u, 24u, 36u, 54u, 81u, 122u, 183u, 274u,
                              411u, 616u, 923u, 1384u, 2076u, 3114u, 4671u, 7007u};
    sc = ksc[l]; re = kre[l]; dense = (l < 10) ? 1 : 0;
}

// Per-point cell setup: EXACT arithmetic of the reference (no FMA contraction).
__device__ __forceinline__ void setup_pt(float2 xy, float scale,
                                         uint32_t& gx, uint32_t& gy,
                                         float& fx, float& fy) {
    const float px  = __fadd_rn(__fmul_rn(xy.x, scale), 0.5f);
    const float py  = __fadd_rn(__fmul_rn(xy.y, scale), 0.5f);
    const float fpx = floorf(px);
    const float fpy = floorf(py);
    fx = px - fpx;
    fy = py - fpy;
    gx = (uint32_t)fpx;
    gy = (uint32_t)fpy;
}

// Reference-order accumulation: (0,0),(0,1),(1,0),(1,1). Passed bit-identical
// in R5 (absmax 4.768e-7, same as encode_one).
__device__ __forceinline__ float2 acc_quad(float2 v00, float2 v01, float2 v10, float2 v11,
                                           float fx, float fy) {
    const float w00 = (1.0f - fx) * (1.0f - fy);
    const float w01 = (1.0f - fx) * fy;
    const float w10 = fx * (1.0f - fy);
    const float w11 = fx * fy;
    float ax = fmaf(v00.x, w00, 0.0f);
    float ay = fmaf(v00.y, w00, 0.0f);
    ax = fmaf(v01.x, w01, ax); ay = fmaf(v01.y, w01, ay);
    ax = fmaf(v10.x, w10, ax); ay = fmaf(v10.y, w10, ay);
    ax = fmaf(v11.x, w11, ax); ay = fmaf(v11.y, w11, ay);
    return make_float2(ax, ay);
}

// Fetch table entry idx via aligned 16B load + half-select (idx&1).
// 16B at tab4[idx>>1] covers entries {idx&~1, idx|1}; never crosses a line.
__device__ __forceinline__ float2 entry16(const float4* __restrict__ tab4, uint32_t idx) {
    const float4 P = tab4[idx >> 1];
    return (idx & 1u) ? make_float2(P.z, P.w) : make_float2(P.x, P.y);
}

// ---- original scalar-gather encode (merge + fallback; R3-verbatim path). ----
__device__ __forceinline__ float2 encode_one(float2 xy, float scale, uint32_t res,
                                             int dense, const float2* __restrict__ tab) {
    const float px  = __fadd_rn(__fmul_rn(xy.x, scale), 0.5f);
    const float py  = __fadd_rn(__fmul_rn(xy.y, scale), 0.5f);
    const float fpx = floorf(px);
    const float fpy = floorf(py);
    const float fx  = px - fpx;
    const float fy  = py - fpy;
    const uint32_t gx = (uint32_t)fpx;
    const uint32_t gy = (uint32_t)fpy;

    float ax = 0.0f, ay = 0.0f;
#pragma unroll
    for (int dx = 0; dx < 2; ++dx) {
        const uint32_t cx = gx + (uint32_t)dx;
        const float    wx = dx ? fx : (1.0f - fx);
#pragma unroll
        for (int dy = 0; dy < 2; ++dy) {
            const uint32_t cy = gy + (uint32_t)dy;
            const float    wy = dy ? fy : (1.0f - fy);
            const uint32_t idx_d = (cx + cy * res) & kTMask;
            const uint32_t idx_h = (cx ^ (cy * kPrimeY)) & kTMask;
            const uint32_t idx   = dense ? idx_d : idx_h;
            const float2   v     = tab[idx];
            const float    w     = wx * wy;
            ax = fmaf(v.x, w, ax);
            ay = fmaf(v.y, w, ay);
        }
    }
    return make_float2(ax, ay);
}

// ---- hash8: levels 8..15, one level per XCD (blockIdx%8), 4 pts/thread. ----
__global__ __launch_bounds__(256) void hash8_kernel(
    const float* __restrict__ x,
    const float* __restrict__ table,
    float2* __restrict__ ws)
{
    const uint32_t slot  = blockIdx.x & 7u;   // -> XCD slot (round-robin dispatch)
    const uint32_t chunk = blockIdx.x >> 3;   // 0..2047
    const int      l     = 8 + (int)slot;
    float sc; uint32_t re; int de;
    level_consts(l, sc, re, de);
    const float4* __restrict__ tab4 = reinterpret_cast<const float4*>(
        reinterpret_cast<const float2*>(table) + ((size_t)l << 19));
    float2* __restrict__ wsl = ws + (size_t)slot * kNPoints;

    const uint32_t base = chunk * 1024u + threadIdx.x;
    const float2* __restrict__ xv = reinterpret_cast<const float2*>(x);

    float2 xy[4];
#pragma unroll
    for (int k = 0; k < 4; ++k)   // NT: don't let the x stream evict the table
        xy[k] = nt_load_f2(xv + base + (uint32_t)k * 256u);

    float2 r[4];
    if (de) {                      // levels 8,9: dense idx = cx + cy*res (no wrap)
#pragma unroll
        for (int k = 0; k < 4; ++k) {
            uint32_t gx, gy; float fx, fy;
            setup_pt(xy[k], sc, gx, gy, fx, fy);
            const uint32_t i00 = gx + gy * re;
            const float2 v00 = entry16(tab4, i00);
            const float2 v10 = entry16(tab4, i00 + 1u);       // shares line w/ v00
            const float2 v01 = entry16(tab4, i00 + re);
            const float2 v11 = entry16(tab4, i00 + re + 1u);  // shares line w/ v01
            r[k] = acc_quad(v00, v01, v10, v11, fx, fy);
        }
    } else {                       // levels 10..15: spatial hash
#pragma unroll
        for (int k = 0; k < 4; ++k) {
            uint32_t gx, gy; float fx, fy;
            setup_pt(xy[k], sc, gx, gy, fx, fy);
            const uint32_t K0 = gy * kPrimeY;
            const uint32_t K1 = K0 + kPrimeY;
            // even gx: idx(gx+1) = idx(gx)^1 -> both 16B loads hit the SAME
            // address (MSHR/L1 merge -> 1 L2 request). Odd gx: 2 requests.
            const float2 v00 = entry16(tab4, (gx        ^ K0) & kTMask);
            const float2 v10 = entry16(tab4, ((gx + 1u) ^ K0) & kTMask);
            const float2 v01 = entry16(tab4, (gx        ^ K1) & kTMask);
            const float2 v11 = entry16(tab4, ((gx + 1u) ^ K1) & kTMask);
            r[k] = acc_quad(v00, v01, v10, v11, fx, fy);
        }
    }

#pragma unroll
    for (int k = 0; k < 4; ++k)   // NT: ws write stream bypasses the table's L2
        nt_store_f2(wsl + base + (uint32_t)k * 256u, r[k]);
}

// ---- merge: R3 VERBATIM (measured 201 us). Dense levels 0-7 inline
//      (1.1 MB of tables, L1/L2-trivial), coalesced ws reads, LDS transpose
//      (stride 36 -> 16B-aligned, conflict-clean b128), coalesced float4 out. --
__global__ __launch_bounds__(256) void merge_kernel(
    const float* __restrict__ x,
    const float* __restrict__ table,
    const float2* __restrict__ ws,    // [8][N]
    float* __restrict__ out)
{
    __shared__ float s[256 * 36];     // 36-float rows: 16B-aligned, bank-clean
    const uint32_t tid = threadIdx.x;
    const uint32_t n   = blockIdx.x * 256u + tid;
    const float2   xy  = reinterpret_cast<const float2*>(x)[n];

#pragma unroll
    for (int l = 0; l < 8; ++l) {
        float sc; uint32_t re; int de;
        level_consts(l, sc, re, de);
        const float2* tab = reinterpret_cast<const float2*>(table) + ((size_t)l << 19);
        const float2 r = encode_one(xy, sc, re, de, tab);
        s[tid * 36 + 2 * l]     = r.x;
        s[tid * 36 + 2 * l + 1] = r.y;
    }
#pragma unroll
    for (int j = 0; j < 8; ++j) {
        const float2 v = ws[(size_t)j * kNPoints + n];   // coalesced
        s[tid * 36 + 2 * (8 + j)]     = v.x;
        s[tid * 36 + 2 * (8 + j) + 1] = v.y;
    }
    __syncthreads();

    float4* outb = reinterpret_cast<float4*>(out + (size_t)blockIdx.x * 8192);
#pragma unroll
    for (int k = 0; k < 8; ++k) {
        const uint32_t q   = tid + (uint32_t)k * 256u;   // float4 index in block tile
        const uint32_t row = q >> 3;                     // point within block
        const uint32_t c   = (q & 7u) * 4u;              // column (floats)
        const float* sp = &s[row * 36 + c];
        outb[q] = make_float4(sp[0], sp[1], sp[2], sp[3]);  // coalesced
    }
}

// ---- Fallback: R1 single kernel (passed at 688 us) if ws is too small. ----
__global__ __launch_bounds__(256) void hashgrid_fwd_fallback(
    const float* __restrict__ x,
    const float* __restrict__ table,
    float* __restrict__ out)
{
    const uint32_t tid = blockIdx.x * blockDim.x + threadIdx.x;
    const uint32_t l   = tid & 15u;
    const uint32_t n   = tid >> 4;
    float sc; uint32_t re; int de;
    level_consts((int)l, sc, re, de);
    const float2 xy = reinterpret_cast<const float2*>(x)[n];
    const float2* tab = reinterpret_cast<const float2*>(table) + ((size_t)l << 19);
    const float2 r = encode_one(xy, sc, re, de, tab);
    reinterpret_cast<float2*>(out)[tid] = r;
}

extern "C" void kernel_launch(void* const* d_in, const int* in_sizes, int n_in,
                              void* d_out, int out_size, void* d_ws, size_t ws_size,
                              hipStream_t stream) {
    const float* x     = (const float*)d_in[0];
    const float* table = (const float*)d_in[1];
    float*       out   = (float*)d_out;

    const size_t need8 = (size_t)8 * kNPoints * sizeof(float2);  // 128 MB

    if (ws_size >= need8) {
        float2* ws = (float2*)d_ws;
        hash8_kernel<<<16384, 256, 0, stream>>>(x, table, ws);
        merge_kernel<<<kNPoints / 256, 256, 0, stream>>>(x, table, ws, out);
    } else {
        hashgrid_fwd_fallback<<<(kNPoints * 16) / 256, 256, 0, stream>>>(x, table, out);
    }
}

// Round 5
// 663.360 us; speedup vs baseline: 1.1130x; 1.1130x over previous
//
#include <hip/hip_runtime.h>
#include <stdint.h>

// HashGrid forward, R7: predicated pair-loads to cut L2 request count.
// R6 post-mortem: float4+select with TWO load instructions gave zero gain
// (312->328 us) -> cross-instruction MSHR merge doesn't reduce TCP/L2
// request occupancy. Three rounds agree hash8 is REQUEST-COUNT-bound
// (~10.5 req/cy/XCD vs ~16 ceiling), insensitive to MLP/occupancy/width.
// R7: for even gx, corners (gx,gx+1) map to adjacent entries h0,h0^1 ->
// ONE aligned 16B load covers both (1 instr, 1 request). For odd gx only,
// a second exec-masked load (if(gx&1)) fetches the other pair -> ~50%
// active lanes. Avg 3 requests/point vs 4 (-25% on critical hash XCDs).
// Dense levels 8/9: same trick keyed on i0&1. x reverted to PLAIN loads
// (R6 FETCH showed NT x-loads bypass LLC -> 128 MB HBM re-fetch; plain lets
// LLC serve 7 of 8 XCD re-reads, and restores R3-like LLC state for merge).
// ws stores stay NT (R3 evidence: NT ws stores coexisted with 201 us merge).
// merge_kernel: R3 VERBATIM, untouched (R5 lesson).
//
// Correctness-critical (unchanged, passed at 4.8e-7): pos = x*scale + 0.5 as
// separate __fmul_rn/__fadd_rn (no FMA -> floor() cell matches numpy);
// acc order (0,0),(0,1),(1,0),(1,1) from 0.0f via acc_quad (bit-identical,
// passed R5/R6); hash wraps via uint32 mul + &mask = numpy uint32 semantics;
// dense levels 8/9 never wrap (max idx 380,071 < 524,288).

constexpr int      kNPoints = 2097152;
constexpr uint32_t kT       = 524288u;      // 2^19
constexpr uint32_t kTMask   = kT - 1u;
constexpr uint32_t kPrimeY  = 2654435761u;  // tcnn 2D spatial-hash prime

__device__ __forceinline__ void nt_store_f2(float2* p, float2 v) {
    union { unsigned long long u; float2 f2; } u; u.f2 = v;
    __builtin_nontemporal_store(u.u, reinterpret_cast<unsigned long long*>(p));
}

// scale = 16*1.5^l - 1, exactly fp32-representable for all 16 levels.
__device__ __host__ inline void level_consts(int l, float& sc, uint32_t& re, int& dense) {
    const float ksc[16] = {
        15.0f, 23.0f, 35.0f, 53.0f, 80.0f, 120.5f, 181.25f, 272.375f,
        409.0625f, 614.09375f, 921.640625f, 1382.9609375f,
        2074.94140625f, 3112.912109375f, 4669.8681640625f, 7005.30224609375f};
    const uint32_t kre[16] = {16u, 24u, 36u, 54u, 81u, 122u, 183u, 274u,
                              411u, 616u, 923u, 1384u, 2076u, 3114u, 4671u, 7007u};
    sc = ksc[l]; re = kre[l]; dense = (l < 10) ? 1 : 0;
}

// Per-point cell setup: EXACT arithmetic of the reference (no FMA contraction).
__device__ __forceinline__ void setup_pt(float2 xy, float scale,
                                         uint32_t& gx, uint32_t& gy,
                                         float& fx, float& fy) {
    const float px  = __fadd_rn(__fmul_rn(xy.x, scale), 0.5f);
    const float py  = __fadd_rn(__fmul_rn(xy.y, scale), 0.5f);
    const float fpx = floorf(px);
    const float fpy = floorf(py);
    fx = px - fpx;
    fy = py - fpy;
    gx = (uint32_t)fpx;
    gy = (uint32_t)fpy;
}

// Reference-order accumulation: (0,0),(0,1),(1,0),(1,1). Bit-identical (R5/R6).
__device__ __forceinline__ float2 acc_quad(float2 v00, float2 v01, float2 v10, float2 v11,
                                           float fx, float fy) {
    const float w00 = (1.0f - fx) * (1.0f - fy);
    const float w01 = (1.0f - fx) * fy;
    const float w10 = fx * (1.0f - fy);
    const float w11 = fx * fy;
    float ax = fmaf(v00.x, w00, 0.0f);
    float ay = fmaf(v00.y, w00, 0.0f);
    ax = fmaf(v01.x, w01, ax); ay = fmaf(v01.y, w01, ay);
    ax = fmaf(v10.x, w10, ax); ay = fmaf(v10.y, w10, ay);
    ax = fmaf(v11.x, w11, ax); ay = fmaf(v11.y, w11, ay);
    return make_float2(ax, ay);
}

// Hash row: fetch corners (gx, gx+1) for key K = cy*prime.
// e = gx&~1 even => h(e)=h0, h(e+1)=h0^1 share the aligned float4 at h0>>1.
// Even gx: 1 load covers both corners. Odd gx: exec-masked 2nd load (~50% lanes).
__device__ __forceinline__ void row_hash(const float4* __restrict__ tab4,
                                         uint32_t gx, uint32_t K,
                                         float2& v0, float2& v1) {
    const uint32_t e   = gx & ~1u;
    const uint32_t odd = gx & 1u;
    const uint32_t h0  = (e ^ K) & kTMask;
    const float4 P0 = tab4[h0 >> 1];
    float4 P1 = P0;
    const uint32_t h2 = ((e + 2u) ^ K) & kTMask;
    if (odd) P1 = tab4[h2 >> 1];                 // exec-masked: odd lanes only
    const uint32_t s0 = (h0 & 1u) ^ odd;         // corner gx   = entry h0^odd (in P0)
    const uint32_t s1 = odd ? (h2 & 1u) : ((h0 & 1u) ^ 1u);  // corner gx+1
    v0 = s0 ? make_float2(P0.z, P0.w) : make_float2(P0.x, P0.y);
    v1 = s1 ? make_float2(P1.z, P1.w) : make_float2(P1.x, P1.y);
}

// Dense row: corners (i0, i0+1), no wrap (levels 8/9 fit T).
// i0 even: both in float4 at i0>>1. i0 odd: exec-masked 2nd load.
__device__ __forceinline__ void row_dense(const float4* __restrict__ tab4,
                                          uint32_t i0,
                                          float2& v0, float2& v1) {
    const uint32_t odd = i0 & 1u;
    const float4 P0 = tab4[i0 >> 1];
    float4 P1 = P0;
    if (odd) P1 = tab4[(i0 >> 1) + 1u];          // exec-masked: odd lanes only
    v0 = odd ? make_float2(P0.z, P0.w) : make_float2(P0.x, P0.y);
    // corner i0+1: even -> half1 of P0; odd -> half0 of P1 (P1 covers i0+1,i0+2)
    v1 = odd ? make_float2(P1.x, P1.y) : make_float2(P0.z, P0.w);
}

// ---- original scalar-gather encode (merge + fallback; R3-verbatim path). ----
__device__ __forceinline__ float2 encode_one(float2 xy, float scale, uint32_t res,
                                             int dense, const float2* __restrict__ tab) {
    const float px  = __fadd_rn(__fmul_rn(xy.x, scale), 0.5f);
    const float py  = __fadd_rn(__fmul_rn(xy.y, scale), 0.5f);
    const float fpx = floorf(px);
    const float fpy = floorf(py);
    const float fx  = px - fpx;
    const float fy  = py - fpy;
    const uint32_t gx = (uint32_t)fpx;
    const uint32_t gy = (uint32_t)fpy;

    float ax = 0.0f, ay = 0.0f;
#pragma unroll
    for (int dx = 0; dx < 2; ++dx) {
        const uint32_t cx = gx + (uint32_t)dx;
        const float    wx = dx ? fx : (1.0f - fx);
#pragma unroll
        for (int dy = 0; dy < 2; ++dy) {
            const uint32_t cy = gy + (uint32_t)dy;
            const float    wy = dy ? fy : (1.0f - fy);
            const uint32_t idx_d = (cx + cy * res) & kTMask;
            const uint32_t idx_h = (cx ^ (cy * kPrimeY)) & kTMask;
            const uint32_t idx   = dense ? idx_d : idx_h;
            const float2   v     = tab[idx];
            const float    w     = wx * wy;
            ax = fmaf(v.x, w, ax);
            ay = fmaf(v.y, w, ay);
        }
    }
    return make_float2(ax, ay);
}

// ---- hash8: levels 8..15, one level per XCD (blockIdx%8), 4 pts/thread. ----
__global__ __launch_bounds__(256) void hash8_kernel(
    const float* __restrict__ x,
    const float* __restrict__ table,
    float2* __restrict__ ws)
{
    const uint32_t slot  = blockIdx.x & 7u;   // -> XCD slot (round-robin dispatch)
    const uint32_t chunk = blockIdx.x >> 3;   // 0..2047
    const int      l     = 8 + (int)slot;
    float sc; uint32_t re; int de;
    level_consts(l, sc, re, de);
    const float4* __restrict__ tab4 = reinterpret_cast<const float4*>(
        reinterpret_cast<const float2*>(table) + ((size_t)l << 19));
    float2* __restrict__ wsl = ws + (size_t)slot * kNPoints;

    const uint32_t base = chunk * 1024u + threadIdx.x;
    const float2* __restrict__ xv = reinterpret_cast<const float2*>(x);

    float2 xy[4];
#pragma unroll
    for (int k = 0; k < 4; ++k)   // PLAIN loads: LLC serves 7 of 8 XCD re-reads
        xy[k] = xv[base + (uint32_t)k * 256u];

    float2 r[4];
    if (de) {                      // levels 8,9: dense idx = gx + gy*re (no wrap)
#pragma unroll
        for (int k = 0; k < 4; ++k) {
            uint32_t gx, gy; float fx, fy;
            setup_pt(xy[k], sc, gx, gy, fx, fy);
            const uint32_t i00 = gx + gy * re;
            float2 v00, v10, v01, v11;
            row_dense(tab4, i00,      v00, v10);
            row_dense(tab4, i00 + re, v01, v11);
            r[k] = acc_quad(v00, v01, v10, v11, fx, fy);
        }
    } else {                       // levels 10..15: spatial hash
#pragma unroll
        for (int k = 0; k < 4; ++k) {
            uint32_t gx, gy; float fx, fy;
            setup_pt(xy[k], sc, gx, gy, fx, fy);
            const uint32_t K0 = gy * kPrimeY;
            const uint32_t K1 = K0 + kPrimeY;
            float2 v00, v10, v01, v11;
            row_hash(tab4, gx, K0, v00, v10);
            row_hash(tab4, gx, K1, v01, v11);
            r[k] = acc_quad(v00, v01, v10, v11, fx, fy);
        }
    }

#pragma unroll
    for (int k = 0; k < 4; ++k)   // NT: ws write stream bypasses the table's L2
        nt_store_f2(wsl + base + (uint32_t)k * 256u, r[k]);
}

// ---- merge: R3 VERBATIM (measured 201 us). Dense levels 0-7 inline
//      (1.1 MB of tables, L1/L2-trivial), coalesced ws reads, LDS transpose
//      (stride 36 -> 16B-aligned, conflict-clean b128), coalesced float4 out. --
__global__ __launch_bounds__(256) void merge_kernel(
    const float* __restrict__ x,
    const float* __restrict__ table,
    const float2* __restrict__ ws,    // [8][N]
    float* __restrict__ out)
{
    __shared__ float s[256 * 36];     // 36-float rows: 16B-aligned, bank-clean
    const uint32_t tid = threadIdx.x;
    const uint32_t n   = blockIdx.x * 256u + tid;
    const float2   xy  = reinterpret_cast<const float2*>(x)[n];

#pragma unroll
    for (int l = 0; l < 8; ++l) {
        float sc; uint32_t re; int de;
        level_consts(l, sc, re, de);
        const float2* tab = reinterpret_cast<const float2*>(table) + ((size_t)l << 19);
        const float2 r = encode_one(xy, sc, re, de, tab);
        s[tid * 36 + 2 * l]     = r.x;
        s[tid * 36 + 2 * l + 1] = r.y;
    }
#pragma unroll
    for (int j = 0; j < 8; ++j) {
        const float2 v = ws[(size_t)j * kNPoints + n];   // coalesced
        s[tid * 36 + 2 * (8 + j)]     = v.x;
        s[tid * 36 + 2 * (8 + j) + 1] = v.y;
    }
    __syncthreads();

    float4* outb = reinterpret_cast<float4*>(out + (size_t)blockIdx.x * 8192);
#pragma unroll
    for (int k = 0; k < 8; ++k) {
        const uint32_t q   = tid + (uint32_t)k * 256u;   // float4 index in block tile
        const uint32_t row = q >> 3;                     // point within block
        const uint32_t c   = (q & 7u) * 4u;              // column (floats)
        const float* sp = &s[row * 36 + c];
        outb[q] = make_float4(sp[0], sp[1], sp[2], sp[3]);  // coalesced
    }
}

// ---- Fallback: R1 single kernel (passed at 688 us) if ws is too small. ----
__global__ __launch_bounds__(256) void hashgrid_fwd_fallback(
    const float* __restrict__ x,
    const float* __restrict__ table,
    float* __restrict__ out)
{
    const uint32_t tid = blockIdx.x * blockDim.x + threadIdx.x;
    const uint32_t l   = tid & 15u;
    const uint32_t n   = tid >> 4;
    float sc; uint32_t re; int de;
    level_consts((int)l, sc, re, de);
    const float2 xy = reinterpret_cast<const float2*>(x)[n];
    const float2* tab = reinterpret_cast<const float2*>(table) + ((size_t)l << 19);
    const float2 r = encode_one(xy, sc, re, de, tab);
    reinterpret_cast<float2*>(out)[tid] = r;
}

extern "C" void kernel_launch(void* const* d_in, const int* in_sizes, int n_in,
                              void* d_out, int out_size, void* d_ws, size_t ws_size,
                              hipStream_t stream) {
    const float* x     = (const float*)d_in[0];
    const float* table = (const float*)d_in[1];
    float*       out   = (float*)d_out;

    const size_t need8 = (size_t)8 * kNPoints * sizeof(float2);  // 128 MB

    if (ws_size >= need8) {
        float2* ws = (float2*)d_ws;
        hash8_kernel<<<16384, 256, 0, stream>>>(x, table, ws);
        merge_kernel<<<kNPoints / 256, 256, 0, stream>>>(x, table, ws, out);
    } else {
        hashgrid_fwd_fallback<<<(kNPoints * 16) / 256, 256, 0, stream>>>(x, table, out);
    }
}